// Round 4
// baseline (675.731 us; speedup 1.0000x reference)
//
#include <hip/hip_runtime.h>
#include <cstddef>
#include <cstdint>

// Problem constants
static constexpr int BB   = 2;
static constexpr int SS   = 384;
static constexpr int HH   = 768;
static constexpr int NHD  = 12;
static constexpr int ROWS = BB * SS;       // 768
#define SCALE_F 0.125f                     // 1/sqrt(64)

static __device__ __forceinline__ unsigned short f2bf(float x) {
    unsigned int b = __float_as_uint(x);
    b = (b + 0x7fffu + ((b >> 16) & 1u)) >> 16;   // round-to-nearest-even
    return (unsigned short)b;
}

// ---------------------------------------------------------------------------
// 64x64-tile fp32 GEMM body with register prefetch (R2-proven):
// C[i,o] = sum_k A[i,k]*W[o,k] + bias[o] (+ add[i,o])
// ---------------------------------------------------------------------------
__device__ __forceinline__ void gemm_body(const float* __restrict__ A,
                                          const float* __restrict__ W,
                                          const float* __restrict__ bias,
                                          const float* __restrict__ addsrc,
                                          float* __restrict__ C) {
    __shared__ float aT[16][68];
    __shared__ float wT[16][68];
    const int tid = threadIdx.x;
    const int i0 = blockIdx.y * 64, o0 = blockIdx.x * 64;
    const int tr = (tid >> 4) << 2;     // 0..60
    const int tc = (tid & 15) << 2;     // 0..60
    const int lr = tid >> 2;            // 0..63
    const int lk = (tid & 3) << 2;      // 0,4,8,12

    float4 av = *(const float4*)&A[(size_t)(i0 + lr) * HH + lk];
    float4 wv = *(const float4*)&W[(size_t)(o0 + lr) * HH + lk];
    float acc[4][4] = {};
    for (int k0 = 0; k0 < HH; k0 += 16) {
        __syncthreads();
        aT[lk + 0][lr] = av.x; aT[lk + 1][lr] = av.y; aT[lk + 2][lr] = av.z; aT[lk + 3][lr] = av.w;
        wT[lk + 0][lr] = wv.x; wT[lk + 1][lr] = wv.y; wT[lk + 2][lr] = wv.z; wT[lk + 3][lr] = wv.w;
        __syncthreads();
        if (k0 + 16 < HH) {   // prefetch next K-chunk while computing this one
            av = *(const float4*)&A[(size_t)(i0 + lr) * HH + k0 + 16 + lk];
            wv = *(const float4*)&W[(size_t)(o0 + lr) * HH + k0 + 16 + lk];
        }
#pragma unroll
        for (int kk = 0; kk < 16; kk++) {
            const float4 a4 = *(const float4*)&aT[kk][tr];
            const float4 w4 = *(const float4*)&wT[kk][tc];
            const float ab[4] = {a4.x, a4.y, a4.z, a4.w};
            const float wb[4] = {w4.x, w4.y, w4.z, w4.w};
#pragma unroll
            for (int r = 0; r < 4; r++)
#pragma unroll
                for (int c = 0; c < 4; c++)
                    acc[r][c] = fmaf(ab[r], wb[c], acc[r][c]);
        }
    }
#pragma unroll
    for (int r = 0; r < 4; r++) {
        const int orow = i0 + tr + r;
#pragma unroll
        for (int c = 0; c < 4; c++) {
            float v = acc[r][c] + bias[o0 + tc + c];
            if (addsrc) v += addsrc[(size_t)orow * HH + o0 + tc + c];
            C[(size_t)orow * HH + o0 + tc + c] = v;
        }
    }
}

__global__ __launch_bounds__(256) void k_gemm_qkv(const float* __restrict__ A,
                                                  const float* __restrict__ Wq, const float* __restrict__ bq,
                                                  const float* __restrict__ Wk, const float* __restrict__ bk,
                                                  const float* __restrict__ Wv, const float* __restrict__ bv,
                                                  float* __restrict__ qo, float* __restrict__ ko,
                                                  float* __restrict__ vo) {
    const int z = blockIdx.z;
    const float* W = (z == 0) ? Wq : (z == 1) ? Wk : Wv;
    const float* bias = (z == 0) ? bq : (z == 1) ? bk : bv;
    float* C = (z == 0) ? qo : (z == 1) ? ko : vo;
    gemm_body(A, W, bias, nullptr, C);
}

__global__ __launch_bounds__(256) void k_gemm_out(const float* __restrict__ A,
                                                  const float* __restrict__ W,
                                                  const float* __restrict__ bias,
                                                  const float* __restrict__ addsrc,
                                                  float* __restrict__ C) {
    gemm_body(A, W, bias, addsrc, C);
}

// ---------------------------------------------------------------------------
// U[row, h, e] = sum_d (q[row, h*64+d] + v[h,d]) * Wr[h*64+d, e]   (bf16 out)
// grid: (etile 12, rowtile 12, h 12), block 256
// ---------------------------------------------------------------------------
__global__ __launch_bounds__(256) void k_uproj(const float* __restrict__ q,
                                               const float* __restrict__ Wr,
                                               const float* __restrict__ vhead,
                                               unsigned short* __restrict__ U) {
    const int h = blockIdx.z;
    const int e0 = blockIdx.x * 64, r0 = blockIdx.y * 64;
    __shared__ float qT[64][68];   // qT[d][r]
    __shared__ float wE[64][68];   // wE[d][e]
    const int tid = threadIdx.x;
    const int lr = tid >> 2;            // 0..63
    const int bc = (tid & 3) * 16;      // 0,16,32,48
#pragma unroll
    for (int m = 0; m < 4; m++) {
        const int col = bc + m * 4;
        const float4 qv = *(const float4*)&q[(size_t)(r0 + lr) * HH + h * 64 + col];
        const float4 vv = *(const float4*)&vhead[h * 64 + col];
        qT[col + 0][lr] = qv.x + vv.x;
        qT[col + 1][lr] = qv.y + vv.y;
        qT[col + 2][lr] = qv.z + vv.z;
        qT[col + 3][lr] = qv.w + vv.w;
        const float4 wv = *(const float4*)&Wr[(size_t)(h * 64 + lr) * HH + e0 + col];
        *(float4*)&wE[lr][col] = wv;
    }
    __syncthreads();
    const int tr = (tid >> 4) << 2;
    const int tc = (tid & 15) << 2;
    float acc[4][4] = {};
#pragma unroll 8
    for (int d = 0; d < 64; d++) {
        const float4 a4 = *(const float4*)&qT[d][tr];
        const float4 b4 = *(const float4*)&wE[d][tc];
        const float ab[4] = {a4.x, a4.y, a4.z, a4.w};
        const float bb[4] = {b4.x, b4.y, b4.z, b4.w};
#pragma unroll
        for (int r = 0; r < 4; r++)
#pragma unroll
            for (int c = 0; c < 4; c++)
                acc[r][c] = fmaf(ab[r], bb[c], acc[r][c]);
    }
#pragma unroll
    for (int r = 0; r < 4; r++) {
        ushort4 o;
        o.x = f2bf(acc[r][0]); o.y = f2bf(acc[r][1]);
        o.z = f2bf(acc[r][2]); o.w = f2bf(acc[r][3]);
        *(ushort4*)&U[(size_t)(r0 + tr + r) * (NHD * HH) + (size_t)h * HH + e0 + tc] = o;
    }
}

// cb[row, h] = sum_d (q[row,h*64+d] + v[h,d]) * br[h*64+d]
__global__ void k_cb(const float* __restrict__ q, const float* __restrict__ vhead,
                     const float* __restrict__ br, float* __restrict__ cb) {
    const int t = blockIdx.x * 256 + threadIdx.x;
    if (t >= ROWS * NHD) return;
    const int row = t / NHD, h = t - row * NHD;
    float s = 0.f;
    for (int d = 0; d < 64; d++) {
        const int c = h * 64 + d;
        s = fmaf(q[(size_t)row * HH + c] + vhead[c], br[c], s);
    }
    cb[t] = s;
}

// ---------------------------------------------------------------------------
// AC scores GEMM: sc[b,i,h,j] = sum_d (q[b,i,hd]+u[h,d]) * k[b,j,hd] + cb[b,i,h]
// grid: (jtile 6, itile 6, b*NH 24), block 256
// ---------------------------------------------------------------------------
__global__ __launch_bounds__(256) void k_ac(const float* __restrict__ q,
                                            const float* __restrict__ kk,
                                            const float* __restrict__ uvec,
                                            const float* __restrict__ cb,
                                            float* __restrict__ sc) {
    const int bh = blockIdx.z;
    const int b = bh / NHD, h = bh - b * NHD;
    const int i0 = blockIdx.y * 64, j0 = blockIdx.x * 64;
    __shared__ float qT[64][68];   // qT[d][i]
    __shared__ float kT[64][68];   // kT[d][j]
    const int tid = threadIdx.x;
    const int lr = tid >> 2;
    const int bc = (tid & 3) * 16;
#pragma unroll
    for (int m = 0; m < 4; m++) {
        const int col = bc + m * 4;
        const float4 qv = *(const float4*)&q[(size_t)(b * SS + i0 + lr) * HH + h * 64 + col];
        const float4 uv = *(const float4*)&uvec[h * 64 + col];
        qT[col + 0][lr] = qv.x + uv.x;
        qT[col + 1][lr] = qv.y + uv.y;
        qT[col + 2][lr] = qv.z + uv.z;
        qT[col + 3][lr] = qv.w + uv.w;
        const float4 kv = *(const float4*)&kk[(size_t)(b * SS + j0 + lr) * HH + h * 64 + col];
        kT[col + 0][lr] = kv.x;
        kT[col + 1][lr] = kv.y;
        kT[col + 2][lr] = kv.z;
        kT[col + 3][lr] = kv.w;
    }
    __syncthreads();
    const int tr = (tid >> 4) << 2;
    const int tc = (tid & 15) << 2;
    float acc[4][4] = {};
#pragma unroll 8
    for (int d = 0; d < 64; d++) {
        const float4 a4 = *(const float4*)&qT[d][tr];
        const float4 b4 = *(const float4*)&kT[d][tc];
        const float ab[4] = {a4.x, a4.y, a4.z, a4.w};
        const float bb[4] = {b4.x, b4.y, b4.z, b4.w};
#pragma unroll
        for (int r = 0; r < 4; r++)
#pragma unroll
            for (int c = 0; c < 4; c++)
                acc[r][c] = fmaf(ab[r], bb[c], acc[r][c]);
    }
#pragma unroll
    for (int r = 0; r < 4; r++) {
        const int i = i0 + tr + r;
        const float cbr = cb[(b * SS + i) * NHD + h];
        float4 o;
        o.x = acc[r][0] + cbr; o.y = acc[r][1] + cbr;
        o.z = acc[r][2] + cbr; o.w = acc[r][3] + cbr;
        *(float4*)&sc[((size_t)(b * SS + i) * NHD + h) * SS + j0 + tc] = o;
    }
}

// ---------------------------------------------------------------------------
// BD + softmax: one block per (b,i), 384 threads (6 waves), U in bf16 LDS.
// LDS = 18.0 (Ul) + 18.4 (sc) + 1.5 (ext) = 37.9 KB -> 3-4 blocks/CU ->
// all 768 blocks co-resident in one round (no tail).
// ---------------------------------------------------------------------------
__global__ __launch_bounds__(384, 5) void k_bd(const float* __restrict__ rpe,
                                               const unsigned short* __restrict__ U,
                                               const int* __restrict__ mask,
                                               float* __restrict__ scP) {
    const int i = blockIdx.x;          // 0..383
    const int b = blockIdx.y;          // 0..1
    const int row = b * SS + i;
    const int tid = threadIdx.x;

    __shared__ unsigned short Ul[NHD * HH];   // 18 KB (bf16)
    __shared__ float sc[NHD][392];            // 18.4 KB
    __shared__ float extl[SS];                // 1.5 KB

    float* plane = scP + (size_t)row * NHD * SS;

    // stage U row (bf16), AC scores plane, mask
    {
        const uint4* Ur = (const uint4*)(U + (size_t)row * NHD * HH);
        uint4* Uld = (uint4*)Ul;
        for (int t = tid; t < NHD * HH / 8; t += 384) Uld[t] = Ur[t];
        for (int t = tid; t < NHD * 96; t += 384) {
            const int h = t / 96, c4 = (t - h * 96) << 2;
            *(float4*)&sc[h][c4] = *(const float4*)&plane[h * SS + c4];
        }
        extl[tid] = (1.0f - (float)mask[b * SS + tid]) * (-1e18f);
    }
    __syncthreads();

    const int wave = tid >> 6;       // 0..5
    const int lane = tid & 63;

    // ---- BD phase: stream rpe[b,i,:,:] once ----
    {
        const int jsub = lane >> 3;      // 0..7
        const int elane = lane & 7;      // 0..7
        const float* rrow = rpe + (size_t)row * SS * HH;

        for (int g = wave; g < 12; g += 6) {
            const int jbase = g * 32 + jsub;
            const float* rp0 = rrow + (size_t)jbase * HH + (elane << 2);
            float acc[4][NHD] = {};
#pragma unroll 2
            for (int ec = 0; ec < 24; ec++) {
                const int eo = ec << 5;                 // 32 e per chunk
                const float4 t0 = *(const float4*)(rp0 + eo);
                const float4 t1 = *(const float4*)(rp0 + eo + 8 * HH);
                const float4 t2 = *(const float4*)(rp0 + eo + 16 * HH);
                const float4 t3 = *(const float4*)(rp0 + eo + 24 * HH);
                const float rb[4][4] = {{t0.x, t0.y, t0.z, t0.w},
                                        {t1.x, t1.y, t1.z, t1.w},
                                        {t2.x, t2.y, t2.z, t2.w},
                                        {t3.x, t3.y, t3.z, t3.w}};
                const int uo = eo + (elane << 2);       // ushort index, 8B aligned
#pragma unroll
                for (int h = 0; h < NHD; h++) {
                    const uint2 w2 = *(const uint2*)&Ul[h * HH + uo];
                    float ub[4];
                    ub[0] = __uint_as_float(w2.x << 16);
                    ub[1] = __uint_as_float(w2.x & 0xffff0000u);
                    ub[2] = __uint_as_float(w2.y << 16);
                    ub[3] = __uint_as_float(w2.y & 0xffff0000u);
#pragma unroll
                    for (int rr = 0; rr < 4; rr++)
#pragma unroll
                        for (int c = 0; c < 4; c++)
                            acc[rr][h] = fmaf(rb[rr][c], ub[c], acc[rr][h]);
                }
            }
#pragma unroll
            for (int rr = 0; rr < 4; rr++)
#pragma unroll
                for (int h = 0; h < NHD; h++) {
                    float a = acc[rr][h];
                    a += __shfl_xor(a, 1);
                    a += __shfl_xor(a, 2);
                    a += __shfl_xor(a, 4);
                    acc[rr][h] = a;
                }
            if (elane == 0) {
#pragma unroll
                for (int rr = 0; rr < 4; rr++) {
                    const int j = jbase + (rr << 3);
#pragma unroll
                    for (int h = 0; h < NHD; h++)
                        sc[h][j] += acc[rr][h];
                }
            }
        }
    }
    __syncthreads();

    // ---- fused softmax over j per head (scale + mask), write P to plane ----
    {
        for (int h = wave; h < NHD; h += 6) {
            float vbuf[6];
            float m = -1e30f;
#pragma unroll
            for (int t2 = 0; t2 < 6; t2++) {
                vbuf[t2] = sc[h][lane + t2 * 64] * SCALE_F + extl[lane + t2 * 64];
                m = fmaxf(m, vbuf[t2]);
            }
#pragma unroll
            for (int off = 1; off < 64; off <<= 1) m = fmaxf(m, __shfl_xor(m, off));
            float ssum = 0.f;
#pragma unroll
            for (int t2 = 0; t2 < 6; t2++) {
                const float e = __expf(vbuf[t2] - m);
                vbuf[t2] = e;
                ssum += e;
            }
#pragma unroll
            for (int off = 1; off < 64; off <<= 1) ssum += __shfl_xor(ssum, off);
            const float inv = 1.0f / ssum;
#pragma unroll
            for (int t2 = 0; t2 < 6; t2++)
                plane[h * SS + lane + t2 * 64] = vbuf[t2] * inv;
        }
    }
}

// ---------------------------------------------------------------------------
// PV GEMM: ctx[b,i,h*64+d] = sum_j P[b,i,h,j] * val[b,j,h*64+d]
// grid: (itile 6, b*NH 24), block 256
// ---------------------------------------------------------------------------
__global__ __launch_bounds__(256) void k_pv(const float* __restrict__ P,
                                            const float* __restrict__ val,
                                            float* __restrict__ ctx) {
    const int bh = blockIdx.y;
    const int b = bh / NHD, h = bh - b * NHD;
    const int i0 = blockIdx.x * 64;
    __shared__ float pT[64][68];   // pT[j][i]
    __shared__ float vB[64][68];   // vB[j][d]
    const int tid = threadIdx.x;
    const int lr = tid >> 2;
    const int bc = (tid & 3) * 16;
    const int tr = (tid >> 4) << 2;
    const int tc = (tid & 15) << 2;

    float4 pv[4], vv[4];
#pragma unroll
    for (int m = 0; m < 4; m++) {
        const int col = bc + m * 4;
        pv[m] = *(const float4*)&P[((size_t)(b * SS + i0 + lr) * NHD + h) * SS + col];
        vv[m] = *(const float4*)&val[(size_t)(b * SS + lr) * HH + h * 64 + col];
    }
    float acc[4][4] = {};
    for (int jt = 0; jt < SS; jt += 64) {
        __syncthreads();
#pragma unroll
        for (int m = 0; m < 4; m++) {
            const int col = bc + m * 4;
            pT[col + 0][lr] = pv[m].x; pT[col + 1][lr] = pv[m].y;
            pT[col + 2][lr] = pv[m].z; pT[col + 3][lr] = pv[m].w;
            *(float4*)&vB[lr][col] = vv[m];
        }
        __syncthreads();
        if (jt + 64 < SS) {
#pragma unroll
            for (int m = 0; m < 4; m++) {
                const int col = bc + m * 4;
                pv[m] = *(const float4*)&P[((size_t)(b * SS + i0 + lr) * NHD + h) * SS + jt + 64 + col];
                vv[m] = *(const float4*)&val[(size_t)(b * SS + jt + 64 + lr) * HH + h * 64 + col];
            }
        }
#pragma unroll 8
        for (int jj = 0; jj < 64; jj++) {
            const float4 a4 = *(const float4*)&pT[jj][tr];
            const float4 b4 = *(const float4*)&vB[jj][tc];
            const float ab[4] = {a4.x, a4.y, a4.z, a4.w};
            const float bb[4] = {b4.x, b4.y, b4.z, b4.w};
#pragma unroll
            for (int r = 0; r < 4; r++)
#pragma unroll
                for (int c = 0; c < 4; c++)
                    acc[r][c] = fmaf(ab[r], bb[c], acc[r][c]);
        }
    }
#pragma unroll
    for (int r = 0; r < 4; r++) {
        float4 o;
        o.x = acc[r][0]; o.y = acc[r][1]; o.z = acc[r][2]; o.w = acc[r][3];
        *(float4*)&ctx[(size_t)(b * SS + i0 + tr + r) * HH + h * 64 + tc] = o;
    }
}

// ---------------------------------------------------------------------------
// LayerNorm over last dim (768) per row
// ---------------------------------------------------------------------------
__global__ __launch_bounds__(256) void k_ln(const float* __restrict__ x,
                                            const float* __restrict__ g,
                                            const float* __restrict__ bta,
                                            float* __restrict__ o) {
    const int row = blockIdx.x;
    const int tid = threadIdx.x;
    const float* xr = x + (size_t)row * HH;
    __shared__ float red[4];
    const float v0 = xr[tid], v1 = xr[tid + 256], v2 = xr[tid + 512];
    float s = v0 + v1 + v2;
#pragma unroll
    for (int off = 1; off < 64; off <<= 1) s += __shfl_xor(s, off);
    if ((tid & 63) == 0) red[tid >> 6] = s;
    __syncthreads();
    const float mean = (red[0] + red[1] + red[2] + red[3]) * (1.0f / 768.0f);
    const float d0 = v0 - mean, d1 = v1 - mean, d2 = v2 - mean;
    float sq = d0 * d0 + d1 * d1 + d2 * d2;
#pragma unroll
    for (int off = 1; off < 64; off <<= 1) sq += __shfl_xor(sq, off);
    __syncthreads();
    if ((tid & 63) == 0) red[tid >> 6] = sq;
    __syncthreads();
    const float var = (red[0] + red[1] + red[2] + red[3]) * (1.0f / 768.0f);
    const float inv = rsqrtf(var + 1e-6f);
    o[(size_t)row * HH + tid]       = d0 * inv * g[tid]       + bta[tid];
    o[(size_t)row * HH + tid + 256] = d1 * inv * g[tid + 256] + bta[tid + 256];
    o[(size_t)row * HH + tid + 512] = d2 * inv * g[tid + 512] + bta[tid + 512];
}

// ---------------------------------------------------------------------------
extern "C" void kernel_launch(void* const* d_in, const int* in_sizes, int n_in,
                              void* d_out, int out_size, void* d_ws, size_t ws_size,
                              hipStream_t stream) {
    (void)in_sizes; (void)n_in; (void)out_size; (void)ws_size;
    const float* hs   = (const float*)d_in[0];
    const int*   mask = (const int*)d_in[1];
    const float* rpe  = (const float*)d_in[2];
    const float* Wq = (const float*)d_in[3];  const float* bq = (const float*)d_in[4];
    const float* Wk = (const float*)d_in[5];  const float* bk = (const float*)d_in[6];
    const float* Wv = (const float*)d_in[7];  const float* bv = (const float*)d_in[8];
    const float* Wr = (const float*)d_in[9];  const float* br = (const float*)d_in[10];
    const float* u  = (const float*)d_in[11]; const float* v  = (const float*)d_in[12];
    const float* Wf = (const float*)d_in[13]; const float* bf = (const float*)d_in[14];
    const float* lng = (const float*)d_in[15]; const float* lnb = (const float*)d_in[16];
    float* out = (float*)d_out;

    float* wsf     = (float*)d_ws;
    float* q_ws    = wsf;                              // 589824
    float* k_ws    = q_ws   + (size_t)ROWS * HH;
    float* v_ws    = k_ws   + (size_t)ROWS * HH;
    float* ctx_ws  = v_ws   + (size_t)ROWS * HH;
    float* lnin_ws = ctx_ws + (size_t)ROWS * HH;
    float* cb_ws   = lnin_ws + (size_t)ROWS * HH;      // 9216
    float* sc_ws   = cb_ws  + (size_t)ROWS * NHD;      // 3538944 (scores -> P)
    unsigned short* U_ws = (unsigned short*)(sc_ws + (size_t)ROWS * NHD * SS); // bf16 U

    k_gemm_qkv<<<dim3(12, 12, 3), 256, 0, stream>>>(hs, Wq, bq, Wk, bk, Wv, bv,
                                                    q_ws, k_ws, v_ws);
    k_uproj<<<dim3(12, 12, 12), 256, 0, stream>>>(q_ws, Wr, v, U_ws);
    k_cb<<<dim3(36), 256, 0, stream>>>(q_ws, v, br, cb_ws);
    k_ac<<<dim3(6, 6, 24), 256, 0, stream>>>(q_ws, k_ws, u, cb_ws, sc_ws);
    k_bd<<<dim3(SS, BB), 384, 0, stream>>>(rpe, U_ws, mask, sc_ws);
    k_pv<<<dim3(6, 24), 256, 0, stream>>>(sc_ws, v_ws, ctx_ws);
    k_gemm_out<<<dim3(12, 12), 256, 0, stream>>>(ctx_ws, Wf, bf, hs, lnin_ws);
    k_ln<<<dim3(768), 256, 0, stream>>>(lnin_ws, lng, lnb, out);
}

// Round 5
// 331.482 us; speedup vs baseline: 2.0385x; 2.0385x over previous
//
#include <hip/hip_runtime.h>
#include <cstddef>
#include <cstdint>

// Problem constants
static constexpr int BB   = 2;
static constexpr int SS   = 384;
static constexpr int HH   = 768;
static constexpr int NHD  = 12;
static constexpr int ROWS = BB * SS;       // 768
#define SCALE_F 0.125f                     // 1/sqrt(64)

static __device__ __forceinline__ unsigned short f2bf(float x) {
    unsigned int b = __float_as_uint(x);
    b = (b + 0x7fffu + ((b >> 16) & 1u)) >> 16;   // round-to-nearest-even
    return (unsigned short)b;
}

// ---------------------------------------------------------------------------
// 64x64-tile fp32 GEMM body with register prefetch (R2-proven):
// C[i,o] = sum_k A[i,k]*W[o,k] + bias[o] (+ add[i,o])
// ---------------------------------------------------------------------------
__device__ __forceinline__ void gemm_body(const float* __restrict__ A,
                                          const float* __restrict__ W,
                                          const float* __restrict__ bias,
                                          const float* __restrict__ addsrc,
                                          float* __restrict__ C) {
    __shared__ float aT[16][68];
    __shared__ float wT[16][68];
    const int tid = threadIdx.x;
    const int i0 = blockIdx.y * 64, o0 = blockIdx.x * 64;
    const int tr = (tid >> 4) << 2;     // 0..60
    const int tc = (tid & 15) << 2;     // 0..60
    const int lr = tid >> 2;            // 0..63
    const int lk = (tid & 3) << 2;      // 0,4,8,12

    float4 av = *(const float4*)&A[(size_t)(i0 + lr) * HH + lk];
    float4 wv = *(const float4*)&W[(size_t)(o0 + lr) * HH + lk];
    float acc[4][4] = {};
    for (int k0 = 0; k0 < HH; k0 += 16) {
        __syncthreads();
        aT[lk + 0][lr] = av.x; aT[lk + 1][lr] = av.y; aT[lk + 2][lr] = av.z; aT[lk + 3][lr] = av.w;
        wT[lk + 0][lr] = wv.x; wT[lk + 1][lr] = wv.y; wT[lk + 2][lr] = wv.z; wT[lk + 3][lr] = wv.w;
        __syncthreads();
        if (k0 + 16 < HH) {   // prefetch next K-chunk while computing this one
            av = *(const float4*)&A[(size_t)(i0 + lr) * HH + k0 + 16 + lk];
            wv = *(const float4*)&W[(size_t)(o0 + lr) * HH + k0 + 16 + lk];
        }
#pragma unroll
        for (int kk = 0; kk < 16; kk++) {
            const float4 a4 = *(const float4*)&aT[kk][tr];
            const float4 w4 = *(const float4*)&wT[kk][tc];
            const float ab[4] = {a4.x, a4.y, a4.z, a4.w};
            const float wb[4] = {w4.x, w4.y, w4.z, w4.w};
#pragma unroll
            for (int r = 0; r < 4; r++)
#pragma unroll
                for (int c = 0; c < 4; c++)
                    acc[r][c] = fmaf(ab[r], wb[c], acc[r][c]);
        }
    }
#pragma unroll
    for (int r = 0; r < 4; r++) {
        const int orow = i0 + tr + r;
#pragma unroll
        for (int c = 0; c < 4; c++) {
            float v = acc[r][c] + bias[o0 + tc + c];
            if (addsrc) v += addsrc[(size_t)orow * HH + o0 + tc + c];
            C[(size_t)orow * HH + o0 + tc + c] = v;
        }
    }
}

__global__ __launch_bounds__(256) void k_gemm_qkv(const float* __restrict__ A,
                                                  const float* __restrict__ Wq, const float* __restrict__ bq,
                                                  const float* __restrict__ Wk, const float* __restrict__ bk,
                                                  const float* __restrict__ Wv, const float* __restrict__ bv,
                                                  float* __restrict__ qo, float* __restrict__ ko,
                                                  float* __restrict__ vo) {
    const int z = blockIdx.z;
    const float* W = (z == 0) ? Wq : (z == 1) ? Wk : Wv;
    const float* bias = (z == 0) ? bq : (z == 1) ? bk : bv;
    float* C = (z == 0) ? qo : (z == 1) ? ko : vo;
    gemm_body(A, W, bias, nullptr, C);
}

__global__ __launch_bounds__(256) void k_gemm_out(const float* __restrict__ A,
                                                  const float* __restrict__ W,
                                                  const float* __restrict__ bias,
                                                  const float* __restrict__ addsrc,
                                                  float* __restrict__ C) {
    gemm_body(A, W, bias, addsrc, C);
}

// ---------------------------------------------------------------------------
// U[row, h, e] = sum_d (q[row, h*64+d] + v[h,d]) * Wr[h*64+d, e]   (bf16 out)
// grid: (etile 12, rowtile 12, h 12), block 256
// ---------------------------------------------------------------------------
__global__ __launch_bounds__(256) void k_uproj(const float* __restrict__ q,
                                               const float* __restrict__ Wr,
                                               const float* __restrict__ vhead,
                                               unsigned short* __restrict__ U) {
    const int h = blockIdx.z;
    const int e0 = blockIdx.x * 64, r0 = blockIdx.y * 64;
    __shared__ float qT[64][68];   // qT[d][r]
    __shared__ float wE[64][68];   // wE[d][e]
    const int tid = threadIdx.x;
    const int lr = tid >> 2;            // 0..63
    const int bc = (tid & 3) * 16;      // 0,16,32,48
#pragma unroll
    for (int m = 0; m < 4; m++) {
        const int col = bc + m * 4;
        const float4 qv = *(const float4*)&q[(size_t)(r0 + lr) * HH + h * 64 + col];
        const float4 vv = *(const float4*)&vhead[h * 64 + col];
        qT[col + 0][lr] = qv.x + vv.x;
        qT[col + 1][lr] = qv.y + vv.y;
        qT[col + 2][lr] = qv.z + vv.z;
        qT[col + 3][lr] = qv.w + vv.w;
        const float4 wv = *(const float4*)&Wr[(size_t)(h * 64 + lr) * HH + e0 + col];
        *(float4*)&wE[lr][col] = wv;
    }
    __syncthreads();
    const int tr = (tid >> 4) << 2;
    const int tc = (tid & 15) << 2;
    float acc[4][4] = {};
#pragma unroll 8
    for (int d = 0; d < 64; d++) {
        const float4 a4 = *(const float4*)&qT[d][tr];
        const float4 b4 = *(const float4*)&wE[d][tc];
        const float ab[4] = {a4.x, a4.y, a4.z, a4.w};
        const float bb[4] = {b4.x, b4.y, b4.z, b4.w};
#pragma unroll
        for (int r = 0; r < 4; r++)
#pragma unroll
            for (int c = 0; c < 4; c++)
                acc[r][c] = fmaf(ab[r], bb[c], acc[r][c]);
    }
#pragma unroll
    for (int r = 0; r < 4; r++) {
        ushort4 o;
        o.x = f2bf(acc[r][0]); o.y = f2bf(acc[r][1]);
        o.z = f2bf(acc[r][2]); o.w = f2bf(acc[r][3]);
        *(ushort4*)&U[(size_t)(r0 + tr + r) * (NHD * HH) + (size_t)h * HH + e0 + tc] = o;
    }
}

// cb[row, h] = sum_d (q[row,h*64+d] + v[h,d]) * br[h*64+d]
__global__ void k_cb(const float* __restrict__ q, const float* __restrict__ vhead,
                     const float* __restrict__ br, float* __restrict__ cb) {
    const int t = blockIdx.x * 256 + threadIdx.x;
    if (t >= ROWS * NHD) return;
    const int row = t / NHD, h = t - row * NHD;
    float s = 0.f;
    for (int d = 0; d < 64; d++) {
        const int c = h * 64 + d;
        s = fmaf(q[(size_t)row * HH + c] + vhead[c], br[c], s);
    }
    cb[t] = s;
}

// ---------------------------------------------------------------------------
// AC scores GEMM: sc[b,i,h,j] = sum_d (q[b,i,hd]+u[h,d]) * k[b,j,hd] + cb[b,i,h]
// grid: (jtile 6, itile 6, b*NH 24), block 256
// ---------------------------------------------------------------------------
__global__ __launch_bounds__(256) void k_ac(const float* __restrict__ q,
                                            const float* __restrict__ kk,
                                            const float* __restrict__ uvec,
                                            const float* __restrict__ cb,
                                            float* __restrict__ sc) {
    const int bh = blockIdx.z;
    const int b = bh / NHD, h = bh - b * NHD;
    const int i0 = blockIdx.y * 64, j0 = blockIdx.x * 64;
    __shared__ float qT[64][68];   // qT[d][i]
    __shared__ float kT[64][68];   // kT[d][j]
    const int tid = threadIdx.x;
    const int lr = tid >> 2;
    const int bc = (tid & 3) * 16;
#pragma unroll
    for (int m = 0; m < 4; m++) {
        const int col = bc + m * 4;
        const float4 qv = *(const float4*)&q[(size_t)(b * SS + i0 + lr) * HH + h * 64 + col];
        const float4 uv = *(const float4*)&uvec[h * 64 + col];
        qT[col + 0][lr] = qv.x + uv.x;
        qT[col + 1][lr] = qv.y + uv.y;
        qT[col + 2][lr] = qv.z + uv.z;
        qT[col + 3][lr] = qv.w + uv.w;
        const float4 kv = *(const float4*)&kk[(size_t)(b * SS + j0 + lr) * HH + h * 64 + col];
        kT[col + 0][lr] = kv.x;
        kT[col + 1][lr] = kv.y;
        kT[col + 2][lr] = kv.z;
        kT[col + 3][lr] = kv.w;
    }
    __syncthreads();
    const int tr = (tid >> 4) << 2;
    const int tc = (tid & 15) << 2;
    float acc[4][4] = {};
#pragma unroll 8
    for (int d = 0; d < 64; d++) {
        const float4 a4 = *(const float4*)&qT[d][tr];
        const float4 b4 = *(const float4*)&kT[d][tc];
        const float ab[4] = {a4.x, a4.y, a4.z, a4.w};
        const float bb[4] = {b4.x, b4.y, b4.z, b4.w};
#pragma unroll
        for (int r = 0; r < 4; r++)
#pragma unroll
            for (int c = 0; c < 4; c++)
                acc[r][c] = fmaf(ab[r], bb[c], acc[r][c]);
    }
#pragma unroll
    for (int r = 0; r < 4; r++) {
        const int i = i0 + tr + r;
        const float cbr = cb[(b * SS + i) * NHD + h];
        float4 o;
        o.x = acc[r][0] + cbr; o.y = acc[r][1] + cbr;
        o.z = acc[r][2] + cbr; o.w = acc[r][3] + cbr;
        *(float4*)&sc[((size_t)(b * SS + i) * NHD + h) * SS + j0 + tc] = o;
    }
}

// ---------------------------------------------------------------------------
// BD + softmax: one block per (b,i), 256 threads (4 waves), U in bf16 LDS.
// LDS = 18.0 (Ul) + 18.4 (sc) + 1.5 (ext) = 37.9 KB -> 4 blocks/CU LDS cap;
// 768 blocks over 256 CUs = 3/CU, all co-resident (one round, no tail).
// NO min-waves hint (R4's (384,5) capped VGPR->48 and spilled ~620 MB).
// ---------------------------------------------------------------------------
__global__ __launch_bounds__(256) void k_bd(const float* __restrict__ rpe,
                                            const unsigned short* __restrict__ U,
                                            const int* __restrict__ mask,
                                            float* __restrict__ scP) {
    const int i = blockIdx.x;          // 0..383
    const int b = blockIdx.y;          // 0..1
    const int row = b * SS + i;
    const int tid = threadIdx.x;

    __shared__ unsigned short Ul[NHD * HH];   // 18 KB (bf16)
    __shared__ float sc[NHD][392];            // 18.4 KB
    __shared__ float extl[SS];                // 1.5 KB

    float* plane = scP + (size_t)row * NHD * SS;

    // stage U row (bf16), AC scores plane, mask
    {
        const uint4* Ur = (const uint4*)(U + (size_t)row * NHD * HH);
        uint4* Uld = (uint4*)Ul;
        for (int t = tid; t < NHD * HH / 8; t += 256) Uld[t] = Ur[t];
        for (int t = tid; t < NHD * 96; t += 256) {
            const int h = t / 96, c4 = (t - h * 96) << 2;
            *(float4*)&sc[h][c4] = *(const float4*)&plane[h * SS + c4];
        }
        for (int t = tid; t < SS; t += 256)
            extl[t] = (1.0f - (float)mask[b * SS + t]) * (-1e18f);
    }
    __syncthreads();

    const int wave = tid >> 6;       // 0..3
    const int lane = tid & 63;

    // ---- BD phase: stream rpe[b,i,:,:] once ----
    {
        const int jsub = lane >> 3;      // 0..7
        const int elane = lane & 7;      // 0..7
        const float* rrow = rpe + (size_t)row * SS * HH;

        for (int g = wave; g < 12; g += 4) {
            const int jbase = g * 32 + jsub;
            const float* rp0 = rrow + (size_t)jbase * HH + (elane << 2);
            float acc[4][NHD] = {};
#pragma unroll 2
            for (int ec = 0; ec < 24; ec++) {
                const int eo = ec << 5;                 // 32 e per chunk
                const float4 t0 = *(const float4*)(rp0 + eo);
                const float4 t1 = *(const float4*)(rp0 + eo + 8 * HH);
                const float4 t2 = *(const float4*)(rp0 + eo + 16 * HH);
                const float4 t3 = *(const float4*)(rp0 + eo + 24 * HH);
                const float rb[4][4] = {{t0.x, t0.y, t0.z, t0.w},
                                        {t1.x, t1.y, t1.z, t1.w},
                                        {t2.x, t2.y, t2.z, t2.w},
                                        {t3.x, t3.y, t3.z, t3.w}};
                const int uo = eo + (elane << 2);       // ushort index, 8B aligned
#pragma unroll
                for (int h = 0; h < NHD; h++) {
                    const uint2 w2 = *(const uint2*)&Ul[h * HH + uo];
                    float ub[4];
                    ub[0] = __uint_as_float(w2.x << 16);
                    ub[1] = __uint_as_float(w2.x & 0xffff0000u);
                    ub[2] = __uint_as_float(w2.y << 16);
                    ub[3] = __uint_as_float(w2.y & 0xffff0000u);
#pragma unroll
                    for (int rr = 0; rr < 4; rr++)
#pragma unroll
                        for (int c = 0; c < 4; c++)
                            acc[rr][h] = fmaf(rb[rr][c], ub[c], acc[rr][h]);
                }
            }
#pragma unroll
            for (int rr = 0; rr < 4; rr++)
#pragma unroll
                for (int h = 0; h < NHD; h++) {
                    float a = acc[rr][h];
                    a += __shfl_xor(a, 1);
                    a += __shfl_xor(a, 2);
                    a += __shfl_xor(a, 4);
                    acc[rr][h] = a;
                }
            if (elane == 0) {
#pragma unroll
                for (int rr = 0; rr < 4; rr++) {
                    const int j = jbase + (rr << 3);
#pragma unroll
                    for (int h = 0; h < NHD; h++)
                        sc[h][j] += acc[rr][h];
                }
            }
        }
    }
    __syncthreads();

    // ---- fused softmax over j per head (scale + mask), write P to plane ----
    {
        for (int h = wave; h < NHD; h += 4) {
            float vbuf[6];
            float m = -1e30f;
#pragma unroll
            for (int t2 = 0; t2 < 6; t2++) {
                vbuf[t2] = sc[h][lane + t2 * 64] * SCALE_F + extl[lane + t2 * 64];
                m = fmaxf(m, vbuf[t2]);
            }
#pragma unroll
            for (int off = 1; off < 64; off <<= 1) m = fmaxf(m, __shfl_xor(m, off));
            float ssum = 0.f;
#pragma unroll
            for (int t2 = 0; t2 < 6; t2++) {
                const float e = __expf(vbuf[t2] - m);
                vbuf[t2] = e;
                ssum += e;
            }
#pragma unroll
            for (int off = 1; off < 64; off <<= 1) ssum += __shfl_xor(ssum, off);
            const float inv = 1.0f / ssum;
#pragma unroll
            for (int t2 = 0; t2 < 6; t2++)
                plane[h * SS + lane + t2 * 64] = vbuf[t2] * inv;
        }
    }
}

// ---------------------------------------------------------------------------
// PV GEMM: ctx[b,i,h*64+d] = sum_j P[b,i,h,j] * val[b,j,h*64+d]
// grid: (itile 6, b*NH 24), block 256
// ---------------------------------------------------------------------------
__global__ __launch_bounds__(256) void k_pv(const float* __restrict__ P,
                                            const float* __restrict__ val,
                                            float* __restrict__ ctx) {
    const int bh = blockIdx.y;
    const int b = bh / NHD, h = bh - b * NHD;
    const int i0 = blockIdx.x * 64;
    __shared__ float pT[64][68];   // pT[j][i]
    __shared__ float vB[64][68];   // vB[j][d]
    const int tid = threadIdx.x;
    const int lr = tid >> 2;
    const int bc = (tid & 3) * 16;
    const int tr = (tid >> 4) << 2;
    const int tc = (tid & 15) << 2;

    float4 pv[4], vv[4];
#pragma unroll
    for (int m = 0; m < 4; m++) {
        const int col = bc + m * 4;
        pv[m] = *(const float4*)&P[((size_t)(b * SS + i0 + lr) * NHD + h) * SS + col];
        vv[m] = *(const float4*)&val[(size_t)(b * SS + lr) * HH + h * 64 + col];
    }
    float acc[4][4] = {};
    for (int jt = 0; jt < SS; jt += 64) {
        __syncthreads();
#pragma unroll
        for (int m = 0; m < 4; m++) {
            const int col = bc + m * 4;
            pT[col + 0][lr] = pv[m].x; pT[col + 1][lr] = pv[m].y;
            pT[col + 2][lr] = pv[m].z; pT[col + 3][lr] = pv[m].w;
            *(float4*)&vB[lr][col] = vv[m];
        }
        __syncthreads();
        if (jt + 64 < SS) {
#pragma unroll
            for (int m = 0; m < 4; m++) {
                const int col = bc + m * 4;
                pv[m] = *(const float4*)&P[((size_t)(b * SS + i0 + lr) * NHD + h) * SS + jt + 64 + col];
                vv[m] = *(const float4*)&val[(size_t)(b * SS + jt + 64 + lr) * HH + h * 64 + col];
            }
        }
#pragma unroll 8
        for (int jj = 0; jj < 64; jj++) {
            const float4 a4 = *(const float4*)&pT[jj][tr];
            const float4 b4 = *(const float4*)&vB[jj][tc];
            const float ab[4] = {a4.x, a4.y, a4.z, a4.w};
            const float bb[4] = {b4.x, b4.y, b4.z, b4.w};
#pragma unroll
            for (int r = 0; r < 4; r++)
#pragma unroll
                for (int c = 0; c < 4; c++)
                    acc[r][c] = fmaf(ab[r], bb[c], acc[r][c]);
        }
    }
#pragma unroll
    for (int r = 0; r < 4; r++) {
        float4 o;
        o.x = acc[r][0]; o.y = acc[r][1]; o.z = acc[r][2]; o.w = acc[r][3];
        *(float4*)&ctx[(size_t)(b * SS + i0 + tr + r) * HH + h * 64 + tc] = o;
    }
}

// ---------------------------------------------------------------------------
// LayerNorm over last dim (768) per row
// ---------------------------------------------------------------------------
__global__ __launch_bounds__(256) void k_ln(const float* __restrict__ x,
                                            const float* __restrict__ g,
                                            const float* __restrict__ bta,
                                            float* __restrict__ o) {
    const int row = blockIdx.x;
    const int tid = threadIdx.x;
    const float* xr = x + (size_t)row * HH;
    __shared__ float red[4];
    const float v0 = xr[tid], v1 = xr[tid + 256], v2 = xr[tid + 512];
    float s = v0 + v1 + v2;
#pragma unroll
    for (int off = 1; off < 64; off <<= 1) s += __shfl_xor(s, off);
    if ((tid & 63) == 0) red[tid >> 6] = s;
    __syncthreads();
    const float mean = (red[0] + red[1] + red[2] + red[3]) * (1.0f / 768.0f);
    const float d0 = v0 - mean, d1 = v1 - mean, d2 = v2 - mean;
    float sq = d0 * d0 + d1 * d1 + d2 * d2;
#pragma unroll
    for (int off = 1; off < 64; off <<= 1) sq += __shfl_xor(sq, off);
    __syncthreads();
    if ((tid & 63) == 0) red[tid >> 6] = sq;
    __syncthreads();
    const float var = (red[0] + red[1] + red[2] + red[3]) * (1.0f / 768.0f);
    const float inv = rsqrtf(var + 1e-6f);
    o[(size_t)row * HH + tid]       = d0 * inv * g[tid]       + bta[tid];
    o[(size_t)row * HH + tid + 256] = d1 * inv * g[tid + 256] + bta[tid + 256];
    o[(size_t)row * HH + tid + 512] = d2 * inv * g[tid + 512] + bta[tid + 512];
}

// ---------------------------------------------------------------------------
extern "C" void kernel_launch(void* const* d_in, const int* in_sizes, int n_in,
                              void* d_out, int out_size, void* d_ws, size_t ws_size,
                              hipStream_t stream) {
    (void)in_sizes; (void)n_in; (void)out_size; (void)ws_size;
    const float* hs   = (const float*)d_in[0];
    const int*   mask = (const int*)d_in[1];
    const float* rpe  = (const float*)d_in[2];
    const float* Wq = (const float*)d_in[3];  const float* bq = (const float*)d_in[4];
    const float* Wk = (const float*)d_in[5];  const float* bk = (const float*)d_in[6];
    const float* Wv = (const float*)d_in[7];  const float* bv = (const float*)d_in[8];
    const float* Wr = (const float*)d_in[9];  const float* br = (const float*)d_in[10];
    const float* u  = (const float*)d_in[11]; const float* v  = (const float*)d_in[12];
    const float* Wf = (const float*)d_in[13]; const float* bf = (const float*)d_in[14];
    const float* lng = (const float*)d_in[15]; const float* lnb = (const float*)d_in[16];
    float* out = (float*)d_out;

    float* wsf     = (float*)d_ws;
    float* q_ws    = wsf;                              // 589824
    float* k_ws    = q_ws   + (size_t)ROWS * HH;
    float* v_ws    = k_ws   + (size_t)ROWS * HH;
    float* ctx_ws  = v_ws   + (size_t)ROWS * HH;
    float* lnin_ws = ctx_ws + (size_t)ROWS * HH;
    float* cb_ws   = lnin_ws + (size_t)ROWS * HH;      // 9216
    float* sc_ws   = cb_ws  + (size_t)ROWS * NHD;      // 3538944 (scores -> P)
    unsigned short* U_ws = (unsigned short*)(sc_ws + (size_t)ROWS * NHD * SS); // bf16 U

    k_gemm_qkv<<<dim3(12, 12, 3), 256, 0, stream>>>(hs, Wq, bq, Wk, bk, Wv, bv,
                                                    q_ws, k_ws, v_ws);
    k_uproj<<<dim3(12, 12, 12), 256, 0, stream>>>(q_ws, Wr, v, U_ws);
    k_cb<<<dim3(36), 256, 0, stream>>>(q_ws, v, br, cb_ws);
    k_ac<<<dim3(6, 6, 24), 256, 0, stream>>>(q_ws, k_ws, u, cb_ws, sc_ws);
    k_bd<<<dim3(SS, BB), 256, 0, stream>>>(rpe, U_ws, mask, sc_ws);
    k_pv<<<dim3(6, 24), 256, 0, stream>>>(sc_ws, v_ws, ctx_ws);
    k_gemm_out<<<dim3(12, 12), 256, 0, stream>>>(ctx_ws, Wf, bf, hs, lnin_ws);
    k_ln<<<dim3(768), 256, 0, stream>>>(lnin_ws, lng, lnb, out);
}